// Round 9
// baseline (231.795 us; speedup 1.0000x reference)
//
#include <hip/hip_runtime.h>

#define H 128
#define W 128
#define NS 8
#define TR 16       // output rows per block
#define LR 24       // TR + 8 halo rows
#define LC 136      // W + 8 halo cols

// Zero-expanded tap table: Gt[dy][s][m] (m padded to 16) =
//   f[s][u][v] with u = dy-4+sy_s, v = m-4+sx_s, zero if u or v outside [0,5).
__device__ float g_gt[9 * 8 * 16];

__global__ __launch_bounds__(256) void build_gt(
    const float* __restrict__ filters,  // [8][5][5]
    const int*   __restrict__ shifts)   // [8][2]
{
    int t = blockIdx.x * 256 + threadIdx.x;
    if (t >= 9 * 8 * 16) return;
    int m  = t & 15;
    int s  = (t >> 4) & 7;
    int dy = t >> 7;
    float val = 0.f;
    if (m < 9) {
        int u = dy - 4 + shifts[2 * s];
        int v = m - 4 + shifts[2 * s + 1];
        if ((unsigned)u < 5u && (unsigned)v < 5u)
            val = filters[s * 25 + u * 5 + v];
    }
    g_gt[t] = val;
}

// out[bc, s, i, j] = sum_{u,v} f[s,u,v] * T[bc, i+u-sy_s, j+v-sx_s], zero-padded.
__global__ __launch_bounds__(512, 3) void shifted_conv_v5(
    const float* __restrict__ tens,     // [256][128][128]
    const int*   __restrict__ shifts,   // [8][2]
    float* __restrict__ out)            // [256][8][128][128]
{
    __shared__ float lds[LR][LC];   // 13056 B

    int blk  = blockIdx.x;
    int tile = blk & 7;             // 8 tiles of 16 rows
    int bc   = blk >> 3;
    int i0   = tile * TR;

    int tid = threadIdx.x;

    // ---- stage rows y in [i0-4, i0+20), cols x in [-4, 132) as float4 slots.
    const float* Timg = tens + (size_t)bc * (H * W);
    #pragma unroll
    for (int rep = 0; rep < 2; ++rep) {
        int slot = tid + rep * 512;
        if (slot < LR * 34) {
            unsigned r  = (unsigned)slot / 34u;   // 0..23
            int      c4 = slot - (int)r * 34;     // 0..33
            int y  = i0 - 4 + (int)r;
            int x4 = c4 - 1;
            float4 v = make_float4(0.f, 0.f, 0.f, 0.f);
            if ((unsigned)y < (unsigned)H && (unsigned)x4 < 32u)
                v = *((const float4*)(Timg + y * W) + x4);
            *(float4*)&lds[r][c4 * 4] = v;
        }
    }

    // Block-uniform shift rows, forced scalar.
    int sy[NS];
    #pragma unroll
    for (int s = 0; s < NS; ++s)
        sy[s] = __builtin_amdgcn_readfirstlane(shifts[2 * s]);

    __syncthreads();

    int it = tid >> 5;      // 0..15 (output row within tile)
    int jt = tid & 31;      // 32 threads per row
    int j0 = jt * 4;        // 4 consecutive outputs per thread

    // ---- read ALL 9 windows upfront into registers (27x ds_read_b128),
    // so the DS wait domain drains once; the FMA phase then only waits on
    // the SMEM tap stream (separate scheduling, hoistable).
    const float* rp = &lds[it][j0];   // 16B-aligned (136%4==0, j0%4==0)
    float w[9][12];
    #pragma unroll
    for (int dy = 0; dy < 9; ++dy) {
        float4 w0 = *(const float4*)(rp + dy * LC);
        float4 w1 = *(const float4*)(rp + dy * LC + 4);
        float4 w2 = *(const float4*)(rp + dy * LC + 8);
        w[dy][0] = w0.x; w[dy][1] = w0.y; w[dy][2]  = w0.z; w[dy][3]  = w0.w;
        w[dy][4] = w1.x; w[dy][5] = w1.y; w[dy][6]  = w1.z; w[dy][7]  = w1.w;
        w[dy][8] = w2.x; w[dy][9] = w2.y; w[dy][10] = w2.z; w[dy][11] = w2.w;
    }

    float acc[NS][4];
    #pragma unroll
    for (int s = 0; s < NS; ++s)
        #pragma unroll
        for (int k = 0; k < 4; ++k) acc[s][k] = 0.f;

    #pragma unroll
    for (int dy = 0; dy < 9; ++dy) {
        #pragma unroll
        for (int s = 0; s < NS; ++s) {
            // block-uniform: u = dy-4+sy_s must be a real filter row
            if ((unsigned)(dy - 4 + sy[s]) < 5u) {
                #pragma unroll
                for (int m = 0; m < 9; ++m) {
                    float fv = g_gt[(dy * 8 + s) * 16 + m];  // uniform -> s_load
                    acc[s][0] = fmaf(fv, w[dy][m + 0], acc[s][0]);
                    acc[s][1] = fmaf(fv, w[dy][m + 1], acc[s][1]);
                    acc[s][2] = fmaf(fv, w[dy][m + 2], acc[s][2]);
                    acc[s][3] = fmaf(fv, w[dy][m + 3], acc[s][3]);
                }
            }
        }
    }

    float* obase = out + (size_t)bc * (NS * H * W) + (size_t)(i0 + it) * W + j0;
    #pragma unroll
    for (int s = 0; s < NS; ++s)
        *(float4*)(obase + (size_t)s * (H * W)) =
            make_float4(acc[s][0], acc[s][1], acc[s][2], acc[s][3]);
}

extern "C" void kernel_launch(void* const* d_in, const int* in_sizes, int n_in,
                              void* d_out, int out_size, void* d_ws, size_t ws_size,
                              hipStream_t stream) {
    const float* tens    = (const float*)d_in[0];
    const float* filters = (const float*)d_in[1];
    const int*   shifts  = (const int*)d_in[2];
    float* out = (float*)d_out;

    build_gt<<<(9 * 8 * 16 + 255) / 256, 256, 0, stream>>>(filters, shifts);
    // 256 bc images x 8 row tiles, 512 threads
    shifted_conv_v5<<<256 * 8, 512, 0, stream>>>(tens, shifts, out);
}